// Round 8
// baseline (26617.422 us; speedup 1.0000x reference)
//
#include <hip/hip_runtime.h>

#define S_LEN 16384
#define BATCH 1024
#define HID   64
#define SBLK  64   // steps per I/O stripe (== wavefront size)

__device__ __forceinline__ float fast_rcp(float x) {
#if __has_builtin(__builtin_amdgcn_rcpf)
  return __builtin_amdgcn_rcpf(x);
#else
  return 1.0f / x;
#endif
}

__device__ __forceinline__ float fast_exp2(float x) {
#if __has_builtin(__builtin_amdgcn_exp2f)
  return __builtin_amdgcn_exp2f(x);
#else
  return __expf(x * 0.69314718055994531f);
#endif
}

// ---- DPP reduce (proven R1/R2/R6) -----------------------------------------
template<int CTRL, int RMASK>
__device__ __forceinline__ float dpp_add(float v) {
  int t = __builtin_amdgcn_update_dpp(0, __float_as_int(v), CTRL, RMASK, 0xF, true);
  return v + __int_as_float(t);
}

// Full 64-lane sum, broadcast to all lanes via readlane(63).
__device__ __forceinline__ float wave_sum_bcast(float v) {
  v = dpp_add<0x111, 0xF>(v);  // row_shr:1
  v = dpp_add<0x112, 0xF>(v);  // row_shr:2
  v = dpp_add<0x114, 0xF>(v);  // row_shr:4
  v = dpp_add<0x118, 0xF>(v);  // row_shr:8
  v = dpp_add<0x142, 0xA>(v);  // row_bcast:15
  v = dpp_add<0x143, 0xC>(v);  // row_bcast:31
  return __int_as_float(__builtin_amdgcn_readlane(__float_as_int(v), 63));
}

__device__ __forceinline__ float rdlane(float v, int l) {
  return __int_as_float(__builtin_amdgcn_readlane(__float_as_int(v), l));
}

// Single wave per block: lanes lockstep — only LDS-op drain needed, no barrier.
__device__ __forceinline__ void lds_fence() {
  asm volatile("s_waitcnt lgkmcnt(0)" ::: "memory");
}

// X-macro over the 16 float4-blocks of the W2 column.
#define FOR_Q(X) X(0) X(1) X(2) X(3) X(4) X(5) X(6) X(7) \
                 X(8) X(9) X(10) X(11) X(12) X(13) X(14) X(15)

__global__ __launch_bounds__(64, 1) void rk4_kernel(
    const float* __restrict__ x,
    const float* __restrict__ W1, const float* __restrict__ b1,
    const float* __restrict__ W2, const float* __restrict__ b2,
    const float* __restrict__ W3, const float* __restrict__ b3,
    float* __restrict__ out)
{
  const int j = threadIdx.x;   // hidden unit / lane index
  const int b = blockIdx.x;    // batch element
  __shared__ float sh[2][HID];

  const float SC = 2.8853900817779268f;  // 2*log2(e)
  const float w1v_s = SC * W1[j];        // W1[0][j]
  const float w1y_s = SC * W1[HID + j];  // W1[1][j]
  const float b1_s  = SC * b1[j];
  const float w3v   = W3[j];             // W3[j][0]
  const float w3m2  = -2.0f * w3v;
  const float bb3   = b3[0];

  // W2 column j folded with -2*SC, held in 64 NAMED scalars (no array!) and
  // pinned via scalar asm. R6 proved array-element pins demote the array to
  // scratch (VGPR_Count=48); named scalars + opaque asm results cannot be
  // rematerialized or demoted.
  const float m2sc = -2.0f * SC;
  float colsum = 0.f;
#define DECLW(q) float wq##q##a, wq##q##b, wq##q##c, wq##q##d;
  FOR_Q(DECLW)
#undef DECLW
#define LOADW(q) { const float* p = W2 + (4 * q) * HID + j;                  \
    float r0 = p[0], r1_ = p[HID], r2_ = p[2 * HID], r3_ = p[3 * HID];       \
    colsum += (r0 + r1_) + (r2_ + r3_);                                      \
    wq##q##a = m2sc * r0; wq##q##b = m2sc * r1_;                             \
    wq##q##c = m2sc * r2_; wq##q##d = m2sc * r3_; }
  FOR_Q(LOADW)
#undef LOADW
#define PINW(q) asm volatile("" : "+v"(wq##q##a), "+v"(wq##q##b), \
                                  "+v"(wq##q##c), "+v"(wq##q##d));
  FOR_Q(PINW)
#undef PINW
  const float w2bias = SC * (b2[j] + colsum);

  // tanh(z) = 1 - 2/(e^{2z}+1); pre-activations carry the 2*log2(e) scale.
  // We broadcast r = rcp(exp2(pre)+1); the "1 - 2*" fold lives in wq##q##*
  // and w2bias (bias absorbs SC*(b2[j]+colsum)). Saturation-safe.
#define MVQ(q) { float4 h4 = s4[q];                    \
    a0 = fmaf(h4.x, wq##q##a, a0);                     \
    a1 = fmaf(h4.y, wq##q##b, a1);                     \
    a2 = fmaf(h4.z, wq##q##c, a2);                     \
    a3 = fmaf(h4.w, wq##q##d, a3); }

#define DERIV(kout, yeff, SHBUF) {                         \
    float pre1 = fmaf((yeff), w1y_s, pv);                  \
    float r1 = fast_rcp(fast_exp2(pre1) + 1.0f);           \
    (SHBUF)[j] = r1;                                       \
    lds_fence();                                           \
    const float4* s4 = (const float4*)(SHBUF);             \
    float a0 = w2bias, a1 = 0.f, a2 = 0.f, a3 = 0.f;       \
    FOR_Q(MVQ)                                             \
    float pre2 = (a0 + a1) + (a2 + a3);                    \
    float r2 = fast_rcp(fast_exp2(pre2) + 1.0f);           \
    float pp = fmaf(w3m2, r2, w3v);                        \
    kout = wave_sum_bcast(pp) + bb3; }

  float y = 0.0f;
  // lane-striped x: lane r holds x[s0 + r][b]; one load per 64 steps
  float xcur = x[(size_t)j * BATCH + b];
  float ybuf = 0.0f;
  size_t obase = (size_t)j * BATCH + b;  // lane's output slot in current stripe

#pragma unroll 1
  for (int blk = 0; blk < S_LEN / SBLK; ++blk) {
    int pf = blk * SBLK + SBLK + j;
    if (pf >= S_LEN) pf = S_LEN - 1;     // clamped prefetch for last stripe
    float xnext = x[(size_t)pf * BATCH + b];

#pragma unroll 1
    for (int t = 0; t < SBLK; ++t) {
      float xv = rdlane(xcur, t);
      float pv = fmaf(xv, w1v_s, b1_s);  // shared by all 4 RK stages
      float k1, k2, k3, k4;
      DERIV(k1, y,                 sh[0])
      DERIV(k2, fmaf(0.5f, k1, y), sh[1])
      DERIV(k3, fmaf(0.5f, k2, y), sh[0])
      DERIV(k4, y + k3,            sh[1])
      y = fmaf((k1 + k4) + 2.0f * (k2 + k3), 1.0f / 6.0f, y);
      if (t == j) ybuf = y;              // stash into this lane's stripe slot
    }
    out[obase] = ybuf;                   // one scatter store per 64 steps
    obase += (size_t)SBLK * BATCH;
    xcur = xnext;
  }
#undef DERIV
#undef MVQ
}

extern "C" void kernel_launch(void* const* d_in, const int* in_sizes, int n_in,
                              void* d_out, int out_size, void* d_ws, size_t ws_size,
                              hipStream_t stream) {
  const float* x  = (const float*)d_in[0];
  const float* W1 = (const float*)d_in[1];
  const float* b1 = (const float*)d_in[2];
  const float* W2 = (const float*)d_in[3];
  const float* b2 = (const float*)d_in[4];
  const float* W3 = (const float*)d_in[5];
  const float* b3 = (const float*)d_in[6];
  float* out = (float*)d_out;

  rk4_kernel<<<BATCH, HID, 0, stream>>>(x, W1, b1, W2, b2, W3, b3, out);
}

// Round 9
// 19008.809 us; speedup vs baseline: 1.4003x; 1.4003x over previous
//
#include <hip/hip_runtime.h>

#define S_LEN 16384
#define BATCH 1024
#define HID   64
#define SBLK  64   // steps per I/O stripe (== wavefront size)

__device__ __forceinline__ float fast_rcp(float x) {
#if __has_builtin(__builtin_amdgcn_rcpf)
  return __builtin_amdgcn_rcpf(x);
#else
  return 1.0f / x;
#endif
}

__device__ __forceinline__ float fast_exp2(float x) {
#if __has_builtin(__builtin_amdgcn_exp2f)
  return __builtin_amdgcn_exp2f(x);
#else
  return __expf(x * 0.69314718055994531f);
#endif
}

// ---- DPP reduce (proven R1/R2/R6/R8) --------------------------------------
template<int CTRL, int RMASK>
__device__ __forceinline__ float dpp_add(float v) {
  int t = __builtin_amdgcn_update_dpp(0, __float_as_int(v), CTRL, RMASK, 0xF, true);
  return v + __int_as_float(t);
}

// Full 64-lane sum, broadcast to all lanes via readlane(63).
__device__ __forceinline__ float wave_sum_bcast(float v) {
  v = dpp_add<0x111, 0xF>(v);  // row_shr:1
  v = dpp_add<0x112, 0xF>(v);  // row_shr:2
  v = dpp_add<0x114, 0xF>(v);  // row_shr:4
  v = dpp_add<0x118, 0xF>(v);  // row_shr:8
  v = dpp_add<0x142, 0xA>(v);  // row_bcast:15
  v = dpp_add<0x143, 0xC>(v);  // row_bcast:31
  return __int_as_float(__builtin_amdgcn_readlane(__float_as_int(v), 63));
}

__device__ __forceinline__ float rdlane(float v, int l) {
  return __int_as_float(__builtin_amdgcn_readlane(__float_as_int(v), l));
}

// Single wave per block: lanes lockstep — only LDS-op drain needed, no barrier.
__device__ __forceinline__ void lds_fence() {
  asm volatile("s_waitcnt lgkmcnt(0)" ::: "memory");
}

// tanh(z) = 1 - 2/(e^{2z}+1); pre-activations carry the 2*log2(e) scale so
// e^{2z} = exp2(pre). The "1 - 2*" is folded into the NEXT layer's weights:
// broadcast r = rcp(exp2(pre)+1), use wv[k] = -2*SC*W2[k][j], bias absorbs
// SC*(b2[j] + colsum_j(W2)). Algebraically exact; saturation-safe.
__device__ __forceinline__ float deriv_eval(
    float pv, float yv, float w1y_s, float w2bias, float w3v, float w3m2,
    float bb3, const float (&wv)[HID], float* shbuf, int j)
{
  float pre1 = fmaf(yv, w1y_s, pv);
  float r1 = fast_rcp(fast_exp2(pre1) + 1.0f);   // lane j holds unit j
  shbuf[j] = r1;
  lds_fence();
  const float4* s4 = (const float4*)shbuf;
  float a0 = w2bias, a1 = 0.f, a2 = 0.f, a3 = 0.f;
#pragma unroll
  for (int k = 0; k < HID / 4; ++k) {
    float4 h = s4[k];
    a0 = fmaf(h.x, wv[4 * k + 0], a0);
    a1 = fmaf(h.y, wv[4 * k + 1], a1);
    a2 = fmaf(h.z, wv[4 * k + 2], a2);
    a3 = fmaf(h.w, wv[4 * k + 3], a3);
  }
  float pre2 = (a0 + a1) + (a2 + a3);
  float r2 = fast_rcp(fast_exp2(pre2) + 1.0f);
  float p = fmaf(w3m2, r2, w3v);                 // h2 * W3[j]
  return wave_sum_bcast(p) + bb3;                // k value, uniform
}

// amdgpu_waves_per_eu(1,1): R6/R8 proved the RA caps pressure at ~48 VGPRs
// and spills the W2 column to scratch when only the MIN waves/EU is given
// (launch_bounds' 2nd arg). Max=1 sets the allocator's occupancy target to
// 1 wave/EU (512-VGPR budget) — which is what we physically run anyway
// (1024 blocks on 1024 SIMDs), so this costs nothing.
__global__ __launch_bounds__(64)
__attribute__((amdgpu_waves_per_eu(1, 1)))
void rk4_kernel(
    const float* __restrict__ x,
    const float* __restrict__ W1, const float* __restrict__ b1,
    const float* __restrict__ W2, const float* __restrict__ b2,
    const float* __restrict__ W3, const float* __restrict__ b3,
    float* __restrict__ out)
{
  const int j = threadIdx.x;   // hidden unit / lane index
  const int b = blockIdx.x;    // batch element
  __shared__ float sh[2][HID];

  const float SC = 2.8853900817779268f;  // 2*log2(e)
  const float w1v_s = SC * W1[j];        // W1[0][j]
  const float w1y_s = SC * W1[HID + j];  // W1[1][j]
  const float b1_s  = SC * b1[j];
  const float w3v   = W3[j];             // W3[j][0]
  const float w3m2  = -2.0f * w3v;
  const float bb3   = b3[0];

  // Column j of W2, folded with -2*SC (see deriv_eval comment).
  float wv[HID];
  float colsum = 0.f;
#pragma unroll
  for (int k = 0; k < HID; ++k) {
    float w = W2[k * HID + j];
    colsum += w;
    wv[k] = -2.0f * SC * w;
  }
  const float w2bias = SC * (b2[j] + colsum);

  float y = 0.0f;
  // lane-striped x: lane r holds x[s0 + r][b]; one load per 64 steps
  float xcur = x[(size_t)j * BATCH + b];
  float ybuf = 0.0f;
  size_t obase = (size_t)j * BATCH + b;  // lane's output slot in current stripe

#pragma unroll 1
  for (int blk = 0; blk < S_LEN / SBLK; ++blk) {
    int pf = blk * SBLK + SBLK + j;
    if (pf >= S_LEN) pf = S_LEN - 1;     // clamped prefetch for last stripe
    float xnext = x[(size_t)pf * BATCH + b];

#pragma unroll 1
    for (int t = 0; t < SBLK; ++t) {
      float xv = rdlane(xcur, t);
      float pv = fmaf(xv, w1v_s, b1_s);  // shared by all 4 RK stages
      float k1 = deriv_eval(pv, y,                 w1y_s, w2bias, w3v, w3m2, bb3, wv, sh[0], j);
      float k2 = deriv_eval(pv, fmaf(0.5f, k1, y), w1y_s, w2bias, w3v, w3m2, bb3, wv, sh[1], j);
      float k3 = deriv_eval(pv, fmaf(0.5f, k2, y), w1y_s, w2bias, w3v, w3m2, bb3, wv, sh[0], j);
      float k4 = deriv_eval(pv, y + k3,            w1y_s, w2bias, w3v, w3m2, bb3, wv, sh[1], j);
      y = fmaf((k1 + k4) + 2.0f * (k2 + k3), 1.0f / 6.0f, y);
      if (t == j) ybuf = y;              // stash into this lane's stripe slot
    }
    out[obase] = ybuf;                   // one scatter store per 64 steps
    obase += (size_t)SBLK * BATCH;
    xcur = xnext;
  }
}

extern "C" void kernel_launch(void* const* d_in, const int* in_sizes, int n_in,
                              void* d_out, int out_size, void* d_ws, size_t ws_size,
                              hipStream_t stream) {
  const float* x  = (const float*)d_in[0];
  const float* W1 = (const float*)d_in[1];
  const float* b1 = (const float*)d_in[2];
  const float* W2 = (const float*)d_in[3];
  const float* b2 = (const float*)d_in[4];
  const float* W3 = (const float*)d_in[5];
  const float* b3 = (const float*)d_in[6];
  float* out = (float*)d_out;

  rk4_kernel<<<BATCH, HID, 0, stream>>>(x, W1, b1, W2, b2, W3, b3, out);
}

// Round 11
// 14368.333 us; speedup vs baseline: 1.8525x; 1.3230x over previous
//
#include <hip/hip_runtime.h>

#define S_LEN 16384
#define BATCH 1024
#define HID   64
#define SBLK  64   // steps per I/O stripe (== wavefront size)

typedef float f2 __attribute__((ext_vector_type(2)));

__device__ __forceinline__ float fast_rcp(float x) {
#if __has_builtin(__builtin_amdgcn_rcpf)
  return __builtin_amdgcn_rcpf(x);
#else
  return 1.0f / x;
#endif
}

__device__ __forceinline__ float fast_exp2(float x) {
#if __has_builtin(__builtin_amdgcn_exp2f)
  return __builtin_amdgcn_exp2f(x);
#else
  return __expf(x * 0.69314718055994531f);
#endif
}

// ---- DPP reduce (proven R1..R9) -------------------------------------------
template<int CTRL, int RMASK>
__device__ __forceinline__ float dpp_add(float v) {
  int t = __builtin_amdgcn_update_dpp(0, __float_as_int(v), CTRL, RMASK, 0xF, true);
  return v + __int_as_float(t);
}

// Full 64-lane sum, broadcast to all lanes via readlane(63).
__device__ __forceinline__ float wave_sum_bcast(float v) {
  v = dpp_add<0x111, 0xF>(v);  // row_shr:1
  v = dpp_add<0x112, 0xF>(v);  // row_shr:2
  v = dpp_add<0x114, 0xF>(v);  // row_shr:4
  v = dpp_add<0x118, 0xF>(v);  // row_shr:8
  v = dpp_add<0x142, 0xA>(v);  // row_bcast:15
  v = dpp_add<0x143, 0xC>(v);  // row_bcast:31
  return __int_as_float(__builtin_amdgcn_readlane(__float_as_int(v), 63));
}

__device__ __forceinline__ float rdlane(float v, int l) {
  return __int_as_float(__builtin_amdgcn_readlane(__float_as_int(v), l));
}

// Compiler-only ordering fence. HW needs no s_waitcnt between the ds_write
// and the following ds_reads: same-wave LDS ops complete IN ORDER (lgkm ops
// of the same type return in-order), so the reads observe the write. We only
// must stop the COMPILER from hoisting reads above the store. The compiler
// still emits counted lgkmcnt(N) before each use of read data.
__device__ __forceinline__ void lds_order() {
  asm volatile("" ::: "memory");
}

// 2 exact fp32 FMAs per instruction (VOP3P, gfx90a+). acc += a*b.
__device__ __forceinline__ void pk_fma(f2& acc, f2 a, f2 b) {
  asm("v_pk_fma_f32 %0, %1, %2, %0" : "+v"(acc) : "v"(a), "v"(b));
}

// tanh(z) = 1 - 2/(e^{2z}+1); pre-activations carry the 2*log2(e) scale so
// e^{2z} = exp2(pre). The "1 - 2*" fold lives in wv2 (= -2*SC*W2col) and
// w2bias (absorbs SC*(b2[j]+colsum)). b3 is pre-divided by 64 and folded
// into w3plus so the wave-sum absorbs it. Algebraically exact; saturation-
// safe (exp2->inf => r->0 => h=+1).
__device__ __forceinline__ float deriv_eval(
    float pv, float yv, float w1y_s, float w2bias, float w3plus, float w3m2,
    const f2 (&wv2)[HID / 2], float* shbuf, int j)
{
  float pre1 = fmaf(yv, w1y_s, pv);
  float r1 = fast_rcp(fast_exp2(pre1) + 1.0f);   // lane j holds unit j
  shbuf[j] = r1;
  lds_order();
  const float4* s4 = (const float4*)shbuf;
  f2 acc01 = {w2bias, 0.f}, acc23 = {0.f, 0.f};
#pragma unroll
  for (int k = 0; k < HID / 4; ++k) {
    float4 h = s4[k];
    f2 hlo = {h.x, h.y};
    f2 hhi = {h.z, h.w};
    pk_fma(acc01, hlo, wv2[2 * k + 0]);
    pk_fma(acc23, hhi, wv2[2 * k + 1]);
  }
  float pre2 = (acc01.x + acc23.x) + (acc01.y + acc23.y);
  float r2 = fast_rcp(fast_exp2(pre2) + 1.0f);
  float p = fmaf(w3m2, r2, w3plus);              // h2*W3[j] + b3/64
  return wave_sum_bcast(p);                      // k value, uniform
}

// amdgpu_waves_per_eu(1,1): R9's decisive fix. Only max=1 stops the RA's
// occupancy-target heuristic from capping pressure at ~48 VGPRs and spilling
// the W2 column to scratch (R6/R8). We physically run 1 wave/SIMD anyway.
__global__ __launch_bounds__(64)
__attribute__((amdgpu_waves_per_eu(1, 1)))
void rk4_kernel(
    const float* __restrict__ x,
    const float* __restrict__ W1, const float* __restrict__ b1,
    const float* __restrict__ W2, const float* __restrict__ b2,
    const float* __restrict__ W3, const float* __restrict__ b3,
    float* __restrict__ out)
{
  const int j = threadIdx.x;   // hidden unit / lane index
  const int b = blockIdx.x;    // batch element
  __shared__ float sh[2][HID];

  const float SC = 2.8853900817779268f;  // 2*log2(e)
  const float w1v_s = SC * W1[j];        // W1[0][j]
  const float w1y_s = SC * W1[HID + j];  // W1[1][j]
  const float b1_s  = SC * b1[j];
  const float w3v   = W3[j];             // W3[j][0]
  const float w3m2  = -2.0f * w3v;
  const float w3plus = w3v + b3[0] * (1.0f / 64.0f);  // b3 folded into reduce

  // Column j of W2, folded with -2*SC, as 32 float2 (pk_fma operands).
  f2 wv2[HID / 2];
  float colsum = 0.f;
#pragma unroll
  for (int k = 0; k < HID / 2; ++k) {
    float wa = W2[(2 * k) * HID + j];
    float wb = W2[(2 * k + 1) * HID + j];
    colsum += wa + wb;
    wv2[k].x = -2.0f * SC * wa;
    wv2[k].y = -2.0f * SC * wb;
  }
  const float w2bias = SC * (b2[j] + colsum);

  float y = 0.0f;
  // lane-striped x: lane r holds x[s0 + r][b]; one load per 64 steps
  float xcur = x[(size_t)j * BATCH + b];
  float ybuf = 0.0f;
  size_t obase = (size_t)j * BATCH + b;  // lane's output slot in current stripe

#pragma unroll 1
  for (int blk = 0; blk < S_LEN / SBLK; ++blk) {
    int pf = blk * SBLK + SBLK + j;
    if (pf >= S_LEN) pf = S_LEN - 1;     // clamped prefetch for last stripe
    float xnext = x[(size_t)pf * BATCH + b];

#pragma unroll 1
    for (int t = 0; t < SBLK; ++t) {
      float xv = rdlane(xcur, t);
      float pv = fmaf(xv, w1v_s, b1_s);  // shared by all 4 RK stages
      float k1 = deriv_eval(pv, y,                 w1y_s, w2bias, w3plus, w3m2, wv2, sh[0], j);
      float k2 = deriv_eval(pv, fmaf(0.5f, k1, y), w1y_s, w2bias, w3plus, w3m2, wv2, sh[1], j);
      float k3 = deriv_eval(pv, fmaf(0.5f, k2, y), w1y_s, w2bias, w3plus, w3m2, wv2, sh[0], j);
      float k4 = deriv_eval(pv, y + k3,            w1y_s, w2bias, w3plus, w3m2, wv2, sh[1], j);
      y = fmaf((k1 + k4) + 2.0f * (k2 + k3), 1.0f / 6.0f, y);
      if (t == j) ybuf = y;              // stash into this lane's stripe slot
    }
    out[obase] = ybuf;                   // one scatter store per 64 steps
    obase += (size_t)SBLK * BATCH;
    xcur = xnext;
  }
}

extern "C" void kernel_launch(void* const* d_in, const int* in_sizes, int n_in,
                              void* d_out, int out_size, void* d_ws, size_t ws_size,
                              hipStream_t stream) {
  const float* x  = (const float*)d_in[0];
  const float* W1 = (const float*)d_in[1];
  const float* b1 = (const float*)d_in[2];
  const float* W2 = (const float*)d_in[3];
  const float* b2 = (const float*)d_in[4];
  const float* W3 = (const float*)d_in[5];
  const float* b3 = (const float*)d_in[6];
  float* out = (float*)d_out;

  rk4_kernel<<<BATCH, HID, 0, stream>>>(x, W1, b1, W2, b2, W3, b3, out);
}

// Round 12
// 14250.410 us; speedup vs baseline: 1.8678x; 1.0083x over previous
//
#include <hip/hip_runtime.h>

#define S_LEN 16384
#define BATCH 1024
#define HID   64
#define SBLK  64   // steps per I/O stripe (== wavefront size)

typedef float f2 __attribute__((ext_vector_type(2)));

__device__ __forceinline__ float fast_rcp(float x) {
#if __has_builtin(__builtin_amdgcn_rcpf)
  return __builtin_amdgcn_rcpf(x);
#else
  return 1.0f / x;
#endif
}

__device__ __forceinline__ float fast_exp2(float x) {
#if __has_builtin(__builtin_amdgcn_exp2f)
  return __builtin_amdgcn_exp2f(x);
#else
  return __expf(x * 0.69314718055994531f);
#endif
}

// ---- DPP reduce (proven R1..R11) ------------------------------------------
template<int CTRL, int RMASK>
__device__ __forceinline__ float dpp_add(float v) {
  int t = __builtin_amdgcn_update_dpp(0, __float_as_int(v), CTRL, RMASK, 0xF, true);
  return v + __int_as_float(t);
}

// Full 64-lane sum, broadcast to all lanes via readlane(63).
__device__ __forceinline__ float wave_sum_bcast(float v) {
  v = dpp_add<0x111, 0xF>(v);  // row_shr:1
  v = dpp_add<0x112, 0xF>(v);  // row_shr:2
  v = dpp_add<0x114, 0xF>(v);  // row_shr:4
  v = dpp_add<0x118, 0xF>(v);  // row_shr:8
  v = dpp_add<0x142, 0xA>(v);  // row_bcast:15
  v = dpp_add<0x143, 0xC>(v);  // row_bcast:31
  return __int_as_float(__builtin_amdgcn_readlane(__float_as_int(v), 63));
}

__device__ __forceinline__ float rdlane(float v, int l) {
  return __int_as_float(__builtin_amdgcn_readlane(__float_as_int(v), l));
}

// Compiler-only ordering fence (R11-proven): same-wave LDS ops complete in
// order, so no hardware lgkmcnt(0) drain is needed between the ds_write and
// the broadcast reads — only compiler reordering must be stopped. The
// compiler still emits counted lgkmcnt(N) before each use of read data.
__device__ __forceinline__ void lds_order() {
  asm volatile("" ::: "memory");
}

// 2 exact fp32 FMAs per instruction (VOP3P, gfx90a+). acc += a*b.
__device__ __forceinline__ void pk_fma(f2& acc, f2 a, f2 b) {
  asm("v_pk_fma_f32 %0, %1, %2, %0" : "+v"(acc) : "v"(a), "v"(b));
}

// tanh(z) = 1 - 2/(e^{2z}+1); pre-activations carry the 2*log2(e) scale so
// e^{2z} = exp2(pre). The "1 - 2*" fold lives in wv2 (= -2*SC*W2col) and
// w2bias (absorbs SC*(b2[j]+colsum)); b3/64 is folded into w3plus so the
// wave-sum absorbs it. Algebraically exact; saturation-safe.
//
// Matvec: 4 pk-accumulator chains of depth 8 (R12: dep height 64 -> 32 cyc)
// combined with packed adds.
__device__ __forceinline__ float deriv_eval_pre(
    float pre1, float w2bias, float w3plus, float w3m2,
    const f2 (&wv2)[HID / 2], float* shbuf, int j)
{
  float r1 = fast_rcp(fast_exp2(pre1) + 1.0f);   // lane j holds unit j
  shbuf[j] = r1;
  lds_order();
  const float4* s4 = (const float4*)shbuf;
  f2 acc0 = {w2bias, 0.f}, acc1 = {0.f, 0.f};
  f2 acc2 = {0.f, 0.f},    acc3 = {0.f, 0.f};
#pragma unroll
  for (int k = 0; k < 8; ++k) {
    float4 hA = s4[2 * k];
    float4 hB = s4[2 * k + 1];
    f2 a01 = {hA.x, hA.y};
    f2 a23 = {hA.z, hA.w};
    f2 b01 = {hB.x, hB.y};
    f2 b23 = {hB.z, hB.w};
    pk_fma(acc0, a01, wv2[4 * k + 0]);
    pk_fma(acc1, a23, wv2[4 * k + 1]);
    pk_fma(acc2, b01, wv2[4 * k + 2]);
    pk_fma(acc3, b23, wv2[4 * k + 3]);
  }
  f2 s01 = acc0 + acc1;        // v_pk_add_f32
  f2 s23 = acc2 + acc3;        // v_pk_add_f32
  f2 s = s01 + s23;            // v_pk_add_f32
  float pre2 = s.x + s.y;
  float r2 = fast_rcp(fast_exp2(pre2) + 1.0f);
  float p = fmaf(w3m2, r2, w3plus);              // h2*W3[j] + b3/64
  return wave_sum_bcast(p);                      // k value, uniform
}

// amdgpu_waves_per_eu(1,1): R9's decisive fix. Only max=1 stops the RA's
// occupancy-target heuristic from capping pressure at ~48 VGPRs and spilling
// the W2 column to scratch (R6/R8). We physically run 1 wave/SIMD anyway.
__global__ __launch_bounds__(64)
__attribute__((amdgpu_waves_per_eu(1, 1)))
void rk4_kernel(
    const float* __restrict__ x,
    const float* __restrict__ W1, const float* __restrict__ b1,
    const float* __restrict__ W2, const float* __restrict__ b2,
    const float* __restrict__ W3, const float* __restrict__ b3,
    float* __restrict__ out)
{
  const int j = threadIdx.x;   // hidden unit / lane index
  const int b = blockIdx.x;    // batch element
  __shared__ float sh[2][HID];

  const float SC = 2.8853900817779268f;  // 2*log2(e)
  const float w1v_s = SC * W1[j];        // W1[0][j]
  const float w1y_s = SC * W1[HID + j];  // W1[1][j]
  const float w1y_h = 0.5f * w1y_s;      // for k2/k3 stage-base folding
  const float b1_s  = SC * b1[j];
  const float w3v   = W3[j];             // W3[j][0]
  const float w3m2  = -2.0f * w3v;
  const float w3plus = w3v + b3[0] * (1.0f / 64.0f);  // b3 folded into reduce

  // Column j of W2, folded with -2*SC, as 32 float2 (pk_fma operands).
  f2 wv2[HID / 2];
  float colsum = 0.f;
#pragma unroll
  for (int k = 0; k < HID / 2; ++k) {
    float wa = W2[(2 * k) * HID + j];
    float wb = W2[(2 * k + 1) * HID + j];
    colsum += wa + wb;
    wv2[k].x = -2.0f * SC * wa;
    wv2[k].y = -2.0f * SC * wb;
  }
  const float w2bias = SC * (b2[j] + colsum);

  float y = 0.0f;
  // lane-striped x: lane r holds x[s0 + r][b]; one load per 64 steps
  float xcur = x[(size_t)j * BATCH + b];
  float ybuf = 0.0f;
  size_t obase = (size_t)j * BATCH + b;  // lane's output slot in current stripe

#pragma unroll 1
  for (int blk = 0; blk < S_LEN / SBLK; ++blk) {
    int pf = blk * SBLK + SBLK + j;
    if (pf >= S_LEN) pf = S_LEN - 1;     // clamped prefetch for last stripe
    float xnext = x[(size_t)pf * BATCH + b];

#pragma unroll 1
    for (int t = 0; t < SBLK; ++t) {
      float xv = rdlane(xcur, t);
      float pv = fmaf(xv, w1v_s, b1_s);
      float base = fmaf(y, w1y_s, pv);   // shared by all 4 RK stages
      float k1 = deriv_eval_pre(base,                  w2bias, w3plus, w3m2, wv2, sh[0], j);
      float k2 = deriv_eval_pre(fmaf(k1, w1y_h, base), w2bias, w3plus, w3m2, wv2, sh[1], j);
      float k3 = deriv_eval_pre(fmaf(k2, w1y_h, base), w2bias, w3plus, w3m2, wv2, sh[0], j);
      // partial y is independent of k4 — overlaps k4's deriv/reduce.
      float partial = fmaf(k1 + 2.0f * (k2 + k3), 1.0f / 6.0f, y);
      float k4 = deriv_eval_pre(fmaf(k3, w1y_s, base), w2bias, w3plus, w3m2, wv2, sh[1], j);
      y = fmaf(k4, 1.0f / 6.0f, partial);
      if (t == j) ybuf = y;              // stash into this lane's stripe slot
    }
    out[obase] = ybuf;                   // one scatter store per 64 steps
    obase += (size_t)SBLK * BATCH;
    xcur = xnext;
  }
}

extern "C" void kernel_launch(void* const* d_in, const int* in_sizes, int n_in,
                              void* d_out, int out_size, void* d_ws, size_t ws_size,
                              hipStream_t stream) {
  const float* x  = (const float*)d_in[0];
  const float* W1 = (const float*)d_in[1];
  const float* b1 = (const float*)d_in[2];
  const float* W2 = (const float*)d_in[3];
  const float* b2 = (const float*)d_in[4];
  const float* W3 = (const float*)d_in[5];
  const float* b3 = (const float*)d_in[6];
  float* out = (float*)d_out;

  rk4_kernel<<<BATCH, HID, 0, stream>>>(x, W1, b1, W2, b2, W3, b3, out);
}